// Round 10
// baseline (210.862 us; speedup 1.0000x reference)
//
#include <hip/hip_runtime.h>

#define N_NODES 32768
#define N_EDGES 262144
#define NB      512
#define D       64
#define DE      16
#define NEXP    8

typedef __attribute__((ext_vector_type(8))) short  short8v;
typedef __attribute__((ext_vector_type(4))) float  floatx4;

static __device__ __forceinline__ unsigned short f2bf(float f) {
  unsigned int u = __float_as_uint(f);
  u += 0x7FFFu + ((u >> 16) & 1u);
  return (unsigned short)(u >> 16);
}

// ---------------- sort edges by dst ----------------

__global__ void hist_kernel(const int* __restrict__ dst, int* __restrict__ counts) {
  int i = blockIdx.x * blockDim.x + threadIdx.x;
  if (i < N_EDGES) atomicAdd(&counts[dst[i]], 1);
}

__global__ void scan1_kernel(const int* __restrict__ counts, int* __restrict__ offsets,
                             int* __restrict__ bsums) {
  __shared__ int sm[256];
  int t = threadIdx.x, i = blockIdx.x * 256 + t;
  int v = counts[i];
  sm[t] = v;
  __syncthreads();
  for (int off = 1; off < 256; off <<= 1) {
    int u = (t >= off) ? sm[t - off] : 0;
    __syncthreads();
    sm[t] += u;
    __syncthreads();
  }
  offsets[i] = sm[t] - v;              // in-block exclusive
  if (t == 255) bsums[blockIdx.x] = sm[255];
}

__global__ void scan2_kernel(int* __restrict__ bsums) {
  __shared__ int sm[128];
  int t = threadIdx.x;
  int v = bsums[t];
  sm[t] = v;
  __syncthreads();
  for (int off = 1; off < 128; off <<= 1) {
    int u = (t >= off) ? sm[t - off] : 0;
    __syncthreads();
    sm[t] += u;
    __syncthreads();
  }
  bsums[t] = sm[t] - v;                // exclusive block offsets
}

__global__ void scan3_kernel(int* __restrict__ offsets, const int* __restrict__ bsums,
                             int* __restrict__ cursor) {
  int i = blockIdx.x * 256 + threadIdx.x;
  int v = offsets[i] + bsums[blockIdx.x];
  offsets[i] = v;
  cursor[i]  = v;
  if (i == 0) offsets[N_NODES] = N_EDGES;
}

// light scatter: only ids, no payload (+ fused weight pack in spare thread range)
__global__ void scatter_kernel(const int* __restrict__ dst, const int* __restrict__ src,
                               int* __restrict__ cursor,
                               int* __restrict__ sorted_src, int* __restrict__ edge_order,
                               const float* __restrict__ ex_W1, const float* __restrict__ ex_W2,
                               unsigned short* __restrict__ wpk) {
  int i = blockIdx.x * blockDim.x + threadIdx.x;
  if (i < N_EDGES) {
    int p = atomicAdd(&cursor[dst[i]], 1);
    sorted_src[p] = src[i];
    edge_order[p] = i;
  }
  if (i < NEXP * 2 * D * D) {          // wpk[je][mat][col][k] = W_mat_je[k][col]
    int je  = i >> 13;
    int rem = i & 8191;
    int mat = rem >> 12;
    int cd  = rem & 4095;
    int col = cd >> 6, k = cd & 63;
    const float* W = mat ? ex_W2 : ex_W1;
    wpk[i] = f2bf(W[je * 4096 + k * 64 + col]);
  }
}

// ---------------- tkern v3: 1 node/wave, 4-edge batches, wave-uniform ea loads ----------------
// All edge indices / ea rows are wave-uniform (SGPR-rooted via readfirstlane) -> scalar
// loads; only x rows use the vector pipe (4 independent per batch).

__global__ __launch_bounds__(256, 4) void tkern(
    const float* __restrict__ x, const int* __restrict__ sorted_src,
    const int* __restrict__ edge_order, const float* __restrict__ edge_attr,
    const int* __restrict__ offsets, const float* __restrict__ emb_We,
    float* __restrict__ agg0, unsigned int* __restrict__ Tp) {
  int lane = threadIdx.x & 63;
  int wv = threadIdx.x >> 6;
  int n = blockIdx.x * 4 + wv;
  int st = __builtin_amdgcn_readfirstlane(offsets[n]);
  int en = __builtin_amdgcn_readfirstlane(offsets[n + 1]);

  float tk[DE];
#pragma unroll
  for (int k = 0; k < DE; ++k) tk[k] = 0.f;

  for (int b = st; b < en; b += 4) {
    int e0 = b;
    int e1 = (b + 1 < en) ? b + 1 : b;
    int e2 = (b + 2 < en) ? b + 2 : b;
    int e3 = (b + 3 < en) ? b + 3 : b;
    float m1 = (b + 1 < en) ? 1.f : 0.f;
    float m2 = (b + 2 < en) ? 1.f : 0.f;
    float m3 = (b + 3 < en) ? 1.f : 0.f;
    int s0 = sorted_src[e0], s1 = sorted_src[e1];
    int s2 = sorted_src[e2], s3 = sorted_src[e3];
    int o0 = edge_order[e0], o1 = edge_order[e1];
    int o2 = edge_order[e2], o3 = edge_order[e3];
    const float4* q0 = (const float4*)(edge_attr + (size_t)o0 * DE);
    const float4* q1 = (const float4*)(edge_attr + (size_t)o1 * DE);
    const float4* q2 = (const float4*)(edge_attr + (size_t)o2 * DE);
    const float4* q3 = (const float4*)(edge_attr + (size_t)o3 * DE);
    float4 a0 = q0[0], a1 = q0[1], a2 = q0[2], a3 = q0[3];
    float4 c0 = q1[0], c1 = q1[1], c2 = q1[2], c3 = q1[3];
    float4 d0 = q2[0], d1 = q2[1], d2 = q2[2], d3 = q2[3];
    float4 f0 = q3[0], f1 = q3[1], f2 = q3[2], f3 = q3[3];
    float x0 = x[(size_t)s0 * D + lane];
    float x1 = x[(size_t)s1 * D + lane] * m1;
    float x2 = x[(size_t)s2 * D + lane] * m2;
    float x3 = x[(size_t)s3 * D + lane] * m3;

    tk[0]  += x0 * a0.x; tk[1]  += x0 * a0.y; tk[2]  += x0 * a0.z; tk[3]  += x0 * a0.w;
    tk[4]  += x0 * a1.x; tk[5]  += x0 * a1.y; tk[6]  += x0 * a1.z; tk[7]  += x0 * a1.w;
    tk[8]  += x0 * a2.x; tk[9]  += x0 * a2.y; tk[10] += x0 * a2.z; tk[11] += x0 * a2.w;
    tk[12] += x0 * a3.x; tk[13] += x0 * a3.y; tk[14] += x0 * a3.z; tk[15] += x0 * a3.w;
    tk[0]  += x1 * c0.x; tk[1]  += x1 * c0.y; tk[2]  += x1 * c0.z; tk[3]  += x1 * c0.w;
    tk[4]  += x1 * c1.x; tk[5]  += x1 * c1.y; tk[6]  += x1 * c1.z; tk[7]  += x1 * c1.w;
    tk[8]  += x1 * c2.x; tk[9]  += x1 * c2.y; tk[10] += x1 * c2.z; tk[11] += x1 * c2.w;
    tk[12] += x1 * c3.x; tk[13] += x1 * c3.y; tk[14] += x1 * c3.z; tk[15] += x1 * c3.w;
    tk[0]  += x2 * d0.x; tk[1]  += x2 * d0.y; tk[2]  += x2 * d0.z; tk[3]  += x2 * d0.w;
    tk[4]  += x2 * d1.x; tk[5]  += x2 * d1.y; tk[6]  += x2 * d1.z; tk[7]  += x2 * d1.w;
    tk[8]  += x2 * d2.x; tk[9]  += x2 * d2.y; tk[10] += x2 * d2.z; tk[11] += x2 * d2.w;
    tk[12] += x2 * d3.x; tk[13] += x2 * d3.y; tk[14] += x2 * d3.z; tk[15] += x2 * d3.w;
    tk[0]  += x3 * f0.x; tk[1]  += x3 * f0.y; tk[2]  += x3 * f0.z; tk[3]  += x3 * f0.w;
    tk[4]  += x3 * f1.x; tk[5]  += x3 * f1.y; tk[6]  += x3 * f1.z; tk[7]  += x3 * f1.w;
    tk[8]  += x3 * f2.x; tk[9]  += x3 * f2.y; tk[10] += x3 * f2.z; tk[11] += x3 * f2.w;
    tk[12] += x3 * f3.x; tk[13] += x3 * f3.y; tk[14] += x3 * f3.z; tk[15] += x3 * f3.w;
  }

  {
    float a = 0.f;
#pragma unroll
    for (int k = 0; k < DE; ++k) a += tk[k] * emb_We[k * D + lane];
    agg0[(size_t)n * D + lane] = a;
  }
  unsigned int* tp = Tp + (size_t)n * (D * DE / 2) + lane;
#pragma unroll
  for (int j = 0; j < 8; ++j) {
    unsigned int pk = (unsigned int)f2bf(tk[2 * j]) |
                      ((unsigned int)f2bf(tk[2 * j + 1]) << 16);
    tp[(size_t)j * D] = pk;
  }
}

// ---------------- embedding GNN (j=0, exact f32, feeds routing) ----------------

__global__ __launch_bounds__(256) void gnn0_kernel(
    const float* __restrict__ x, const float* __restrict__ agg0,
    const float* __restrict__ W1, const float* __restrict__ W2,
    const float* __restrict__ bvv, float* __restrict__ graph_emb) {
  __shared__ __align__(16) float w1s[D * D];
  __shared__ __align__(16) float w2s[D * D];
  __shared__ __align__(16) float xs[D * D];
  __shared__ __align__(16) float as2[D * D];
  int b = blockIdx.x;
  int t = threadIdx.x;
  const float4* w1src = (const float4*)W1;
  const float4* w2src = (const float4*)W2;
  const float4* xsrc  = (const float4*)(x    + (size_t)b * D * D);
  const float4* asrc  = (const float4*)(agg0 + (size_t)b * D * D);
#pragma unroll
  for (int r = 0; r < 4; ++r) {
    ((float4*)w1s)[t + r * 256] = w1src[t + r * 256];
    ((float4*)w2s)[t + r * 256] = w2src[t + r * 256];
    ((float4*)xs)[t + r * 256]  = xsrc[t + r * 256];
    ((float4*)as2)[t + r * 256] = asrc[t + r * 256];
  }
  int w = t >> 6, lane = t & 63;
  float bias = bvv[lane];
  __syncthreads();
  float pool = 0.f;
#pragma unroll
  for (int q = 0; q < 4; ++q) {
    int n0 = w * 16 + q * 4;
    float a0 = bias, a1 = bias, a2 = bias, a3 = bias;
#pragma unroll 4
    for (int c4 = 0; c4 < 16; ++c4) {
      float4 x0 = *(const float4*)&xs[(n0 + 0) * D + c4 * 4];
      float4 x1 = *(const float4*)&xs[(n0 + 1) * D + c4 * 4];
      float4 x2 = *(const float4*)&xs[(n0 + 2) * D + c4 * 4];
      float4 x3 = *(const float4*)&xs[(n0 + 3) * D + c4 * 4];
      float4 g0 = *(const float4*)&as2[(n0 + 0) * D + c4 * 4];
      float4 g1 = *(const float4*)&as2[(n0 + 1) * D + c4 * 4];
      float4 g2 = *(const float4*)&as2[(n0 + 2) * D + c4 * 4];
      float4 g3 = *(const float4*)&as2[(n0 + 3) * D + c4 * 4];
      float w10 = w1s[(c4 * 4 + 0) * D + lane];
      float w11 = w1s[(c4 * 4 + 1) * D + lane];
      float w12 = w1s[(c4 * 4 + 2) * D + lane];
      float w13 = w1s[(c4 * 4 + 3) * D + lane];
      float w20 = w2s[(c4 * 4 + 0) * D + lane];
      float w21 = w2s[(c4 * 4 + 1) * D + lane];
      float w22 = w2s[(c4 * 4 + 2) * D + lane];
      float w23 = w2s[(c4 * 4 + 3) * D + lane];
      a0 += x0.x * w10 + x0.y * w11 + x0.z * w12 + x0.w * w13
          + g0.x * w20 + g0.y * w21 + g0.z * w22 + g0.w * w23;
      a1 += x1.x * w10 + x1.y * w11 + x1.z * w12 + x1.w * w13
          + g1.x * w20 + g1.y * w21 + g1.z * w22 + g1.w * w23;
      a2 += x2.x * w10 + x2.y * w11 + x2.z * w12 + x2.w * w13
          + g2.x * w20 + g2.y * w21 + g2.z * w22 + g2.w * w23;
      a3 += x3.x * w10 + x3.y * w11 + x3.z * w12 + x3.w * w13
          + g3.x * w20 + g3.y * w21 + g3.z * w22 + g3.w * w23;
    }
    pool += fmaxf(a0, 0.f) + fmaxf(a1, 0.f) + fmaxf(a2, 0.f) + fmaxf(a3, 0.f);
  }
  __syncthreads();
  xs[w * D + lane] = pool;
  __syncthreads();
  if (w == 0) {
    float s = xs[lane] + xs[D + lane] + xs[2 * D + lane] + xs[3 * D + lane];
    graph_emb[b * D + lane] = s * (1.f / 64.f);
  }
}

// ---------------- experts fused: contract (Tp -> LDS bf16) + MFMA + gating ----------------
// block = graph, 8 waves = 8 experts. Wave je contracts its expert's 64-node agg tile
// from Tp into als[je] (bf16, XOR-swizzled 16B slots), then MFMAs X@W1 + A@W2.
// mfma_f32_16x16x32_bf16: A row=lane&15, k=(lane>>4)*8+i ; C/D col=lane&15, row=(lane>>4)*4+reg

__global__ __launch_bounds__(512) void expert_kernel(
    const float* __restrict__ x, const unsigned int* __restrict__ Tp,
    const float* __restrict__ ex_We, const unsigned short* __restrict__ wpk,
    const float* __restrict__ ex_b, const float* __restrict__ ex_Wout,
    const float* __restrict__ ex_bout,
    const float* __restrict__ graph_emb, const float* __restrict__ Wg,
    const float* __restrict__ bg, float* __restrict__ out) {
  __shared__ __align__(16) short xls[4096];        // X tile bf16, swizzled (8 KB)
  __shared__ __align__(16) short als[NEXP * 4096]; // per-expert agg tiles (64 KB)
  __shared__ float pg[NEXP];
  __shared__ float lg[NEXP];
  int g = blockIdx.x;
  int t = threadIdx.x;
  // stage X tile: f32 -> bf16, swizzled (thread t handles 16B = 8 bf16)
  {
    const float4* xp = (const float4*)(x + (size_t)g * 4096 + (size_t)t * 8);
    float4 va = xp[0], vb = xp[1];
    short8v pk;
    pk[0] = (short)f2bf(va.x); pk[1] = (short)f2bf(va.y);
    pk[2] = (short)f2bf(va.z); pk[3] = (short)f2bf(va.w);
    pk[4] = (short)f2bf(vb.x); pk[5] = (short)f2bf(vb.y);
    pk[6] = (short)f2bf(vb.z); pk[7] = (short)f2bf(vb.w);
    int row = t >> 3, slot = t & 7;
    *(short8v*)((char*)xls + (((row << 3) + (slot ^ (row & 7))) << 4)) = pk;
  }

  int je = t >> 6;
  int lane = t & 63;

  // ---- contract phase: wave je builds als[je] for this graph's 64 nodes ----
  {
    float wr[DE];
#pragma unroll
    for (int k = 0; k < DE; ++k) wr[k] = ex_We[(size_t)je * DE * D + k * D + lane];
    char* abase = (char*)als + (size_t)je * 8192;
    int slot = lane >> 3;
    int within = (lane & 7) << 1;
    for (int i = 0; i < D; i += 2) {
      int nA = g * D + i, nB = nA + 1;
      const unsigned int* ta = Tp + (size_t)nA * 512 + lane;
      const unsigned int* tb = Tp + (size_t)nB * 512 + lane;
      unsigned int pa0 = ta[0],   pa1 = ta[64],  pa2 = ta[128], pa3 = ta[192];
      unsigned int pa4 = ta[256], pa5 = ta[320], pa6 = ta[384], pa7 = ta[448];
      unsigned int pb0 = tb[0],   pb1 = tb[64],  pb2 = tb[128], pb3 = tb[192];
      unsigned int pb4 = tb[256], pb5 = tb[320], pb6 = tb[384], pb7 = tb[448];
      float sA, sB;
      sA  = __uint_as_float(pa0 << 16)         * wr[0];
      sA += __uint_as_float(pa0 & 0xFFFF0000u) * wr[1];
      sA += __uint_as_float(pa1 << 16)         * wr[2];
      sA += __uint_as_float(pa1 & 0xFFFF0000u) * wr[3];
      sA += __uint_as_float(pa2 << 16)         * wr[4];
      sA += __uint_as_float(pa2 & 0xFFFF0000u) * wr[5];
      sA += __uint_as_float(pa3 << 16)         * wr[6];
      sA += __uint_as_float(pa3 & 0xFFFF0000u) * wr[7];
      sA += __uint_as_float(pa4 << 16)         * wr[8];
      sA += __uint_as_float(pa4 & 0xFFFF0000u) * wr[9];
      sA += __uint_as_float(pa5 << 16)         * wr[10];
      sA += __uint_as_float(pa5 & 0xFFFF0000u) * wr[11];
      sA += __uint_as_float(pa6 << 16)         * wr[12];
      sA += __uint_as_float(pa6 & 0xFFFF0000u) * wr[13];
      sA += __uint_as_float(pa7 << 16)         * wr[14];
      sA += __uint_as_float(pa7 & 0xFFFF0000u) * wr[15];
      sB  = __uint_as_float(pb0 << 16)         * wr[0];
      sB += __uint_as_float(pb0 & 0xFFFF0000u) * wr[1];
      sB += __uint_as_float(pb1 << 16)         * wr[2];
      sB += __uint_as_float(pb1 & 0xFFFF0000u) * wr[3];
      sB += __uint_as_float(pb2 << 16)         * wr[4];
      sB += __uint_as_float(pb2 & 0xFFFF0000u) * wr[5];
      sB += __uint_as_float(pb3 << 16)         * wr[6];
      sB += __uint_as_float(pb3 & 0xFFFF0000u) * wr[7];
      sB += __uint_as_float(pb4 << 16)         * wr[8];
      sB += __uint_as_float(pb4 & 0xFFFF0000u) * wr[9];
      sB += __uint_as_float(pb5 << 16)         * wr[10];
      sB += __uint_as_float(pb5 & 0xFFFF0000u) * wr[11];
      sB += __uint_as_float(pb6 << 16)         * wr[12];
      sB += __uint_as_float(pb6 & 0xFFFF0000u) * wr[13];
      sB += __uint_as_float(pb7 << 16)         * wr[14];
      sB += __uint_as_float(pb7 & 0xFFFF0000u) * wr[15];
      *(short*)(abase + (i    ) * 128 + ((slot ^ ( i      & 7)) << 4) + within) = (short)f2bf(sA);
      *(short*)(abase + (i + 1) * 128 + ((slot ^ ((i + 1) & 7)) << 4) + within) = (short)f2bf(sB);
    }
  }
  __syncthreads();

  int r = lane & 15, q = lane >> 4;
  const short* B1 = (const short*)(wpk + (size_t)je * 2 * 4096);
  const short* B2 = B1 + 4096;
  char* abase = (char*)als + (size_t)je * 8192;

  floatx4 acc[4][4];
#pragma unroll
  for (int i = 0; i < 4; ++i)
#pragma unroll
    for (int j = 0; j < 4; ++j) acc[i][j] = (floatx4){0.f, 0.f, 0.f, 0.f};

  // phase 1: X(LDS) @ W1(global)
#pragma unroll
  for (int kk = 0; kk < 2; ++kk) {
    int ko = kk * 32 + q * 8;
    short8v af[4], bf[4];
#pragma unroll
    for (int rt = 0; rt < 4; ++rt) {
      int row = rt * 16 + r;
      int slot = kk * 4 + q;
      af[rt] = *(const short8v*)((char*)xls + (((row << 3) + (slot ^ (row & 7))) << 4));
    }
#pragma unroll
    for (int ct = 0; ct < 4; ++ct) bf[ct] = *(const short8v*)(B1 + (ct * 16 + r) * D + ko);
#pragma unroll
    for (int rt = 0; rt < 4; ++rt)
#pragma unroll
      for (int ct = 0; ct < 4; ++ct)
        acc[rt][ct] = __builtin_amdgcn_mfma_f32_16x16x32_bf16(af[rt], bf[ct], acc[rt][ct], 0, 0, 0);
  }
  // phase 2: AGG(LDS, own-expert tile) @ W2(global)
#pragma unroll
  for (int kk = 0; kk < 2; ++kk) {
    int ko = kk * 32 + q * 8;
    short8v af[4], bf[4];
#pragma unroll
    for (int rt = 0; rt < 4; ++rt) {
      int row = rt * 16 + r;
      int slot = kk * 4 + q;
      af[rt] = *(const short8v*)(abase + (row << 7) + ((slot ^ (row & 7)) << 4));
    }
#pragma unroll
    for (int ct = 0; ct < 4; ++ct) bf[ct] = *(const short8v*)(B2 + (ct * 16 + r) * D + ko);
#pragma unroll
    for (int rt = 0; rt < 4; ++rt)
#pragma unroll
      for (int ct = 0; ct < 4; ++ct)
        acc[rt][ct] = __builtin_amdgcn_mfma_f32_16x16x32_bf16(af[rt], bf[ct], acc[rt][ct], 0, 0, 0);
  }

  // epilogue: relu(+bias), pool over 64 rows, dot with Wout, mean, +bout -> LDS
  float o = 0.f;
#pragma unroll
  for (int ct = 0; ct < 4; ++ct) {
    float bcol = ex_b[je * D + ct * 16 + r];
    float s = 0.f;
#pragma unroll
    for (int rt = 0; rt < 4; ++rt)
#pragma unroll
      for (int rg = 0; rg < 4; ++rg) s += fmaxf(acc[rt][ct][rg] + bcol, 0.f);
    s += __shfl_xor(s, 16);
    s += __shfl_xor(s, 32);
    o += s * ex_Wout[je * D + ct * 16 + r];
  }
#pragma unroll
  for (int off = 8; off >= 1; off >>= 1) o += __shfl_xor(o, off);
  if (lane == 0) pg[je] = o * (1.f / 64.f) + ex_bout[je];
  __syncthreads();

  // fused gating (exact f32): reuse xls as float scratch for graph_emb row
  float* es = (float*)xls;
  if (t < 64) es[t] = graph_emb[g * D + t];
  __syncthreads();
  if (t < NEXP) {
    float v = bg[t];
    for (int d = 0; d < D; ++d) v += es[d] * Wg[d * NEXP + t];
    lg[t] = v;
  }
  __syncthreads();
  if (t < NEXP) {
    float l[NEXP];
    float mx = -1e30f;
#pragma unroll
    for (int e = 0; e < NEXP; ++e) { l[e] = lg[e]; mx = fmaxf(mx, l[e]); }
    float p[NEXP];
    float sum = 0.f;
#pragma unroll
    for (int e = 0; e < NEXP; ++e) { p[e] = expf(l[e] - mx); sum += p[e]; }
    float inv = 1.f / sum;
#pragma unroll
    for (int e = 0; e < NEXP; ++e) p[e] *= inv;
    out[NB + g * NEXP + t] = p[t];
    if (t == 0) {
      int i1 = -1; float v1 = -1e30f;
#pragma unroll
      for (int e = 0; e < NEXP; ++e) if (p[e] > v1) { v1 = p[e]; i1 = e; }
      int i2 = -1; float v2 = -1e30f;
#pragma unroll
      for (int e = 0; e < NEXP; ++e) if (e != i1 && p[e] > v2) { v2 = p[e]; i2 = e; }
      float rr = expf(v2 - v1);
      float n1 = 1.f / (1.f + rr);
      float n2 = rr / (1.f + rr);
      out[g] = n1 * pg[i1] + n2 * pg[i2];
    }
  }
}

// ---------------- launch ----------------

extern "C" void kernel_launch(void* const* d_in, const int* in_sizes, int n_in,
                              void* d_out, int out_size, void* d_ws, size_t ws_size,
                              hipStream_t stream) {
  const float* x         = (const float*)d_in[0];
  const float* edge_attr = (const float*)d_in[1];
  const float* emb_We    = (const float*)d_in[2];
  const float* emb_W1    = (const float*)d_in[3];
  const float* emb_W2    = (const float*)d_in[4];
  const float* emb_b     = (const float*)d_in[5];
  const float* Wg        = (const float*)d_in[6];
  const float* bg        = (const float*)d_in[7];
  const float* ex_We     = (const float*)d_in[8];
  const float* ex_W1     = (const float*)d_in[9];
  const float* ex_W2     = (const float*)d_in[10];
  const float* ex_b      = (const float*)d_in[11];
  const float* ex_Wout   = (const float*)d_in[12];
  const float* ex_bout   = (const float*)d_in[13];
  const int* edge_src    = (const int*)d_in[14];
  const int* edge_dst    = (const int*)d_in[15];

  char* p = (char*)d_ws;
  auto alloc = [&](size_t bytes) {
    char* q = p;
    p += (bytes + 255) & ~(size_t)255;
    return q;
  };
  int*   counts     = (int*)alloc((size_t)N_NODES * 4);
  int*   offsets    = (int*)alloc((size_t)(N_NODES + 1) * 4);
  int*   cursor     = (int*)alloc((size_t)N_NODES * 4);
  int*   bsums      = (int*)alloc(128 * 4);
  int*   sorted_src = (int*)alloc((size_t)N_EDGES * 4);
  int*   edge_order = (int*)alloc((size_t)N_EDGES * 4);
  unsigned int* Tp  = (unsigned int*)alloc((size_t)N_NODES * (D * DE / 2) * 4);  // 64 MB
  float* agg0       = (float*)alloc((size_t)N_NODES * D * 4);
  unsigned short* wpk = (unsigned short*)alloc((size_t)NEXP * 2 * D * D * 2);
  float* graph_emb  = (float*)alloc((size_t)NB * D * 4);

  hipMemsetAsync(counts, 0, (size_t)N_NODES * 4, stream);
  hist_kernel<<<N_EDGES / 256, 256, 0, stream>>>(edge_dst, counts);
  scan1_kernel<<<N_NODES / 256, 256, 0, stream>>>(counts, offsets, bsums);
  scan2_kernel<<<1, 128, 0, stream>>>(bsums);
  scan3_kernel<<<N_NODES / 256, 256, 0, stream>>>(offsets, bsums, cursor);
  scatter_kernel<<<N_EDGES / 256, 256, 0, stream>>>(edge_dst, edge_src, cursor,
                                                    sorted_src, edge_order,
                                                    ex_W1, ex_W2, wpk);
  tkern<<<N_NODES / 4, 256, 0, stream>>>(x, sorted_src, edge_order, edge_attr,
                                         offsets, emb_We, agg0, Tp);
  gnn0_kernel<<<NB, 256, 0, stream>>>(x, agg0, emb_W1, emb_W2, emb_b, graph_emb);
  expert_kernel<<<NB, 512, 0, stream>>>(x, Tp, ex_We, wpk, ex_b, ex_Wout, ex_bout,
                                        graph_emb, Wg, bg, (float*)d_out);
}